// Round 1
// baseline (301.468 us; speedup 1.0000x reference)
//
#include <hip/hip_runtime.h>
#include <hip/hip_cooperative_groups.h>

namespace cg = cooperative_groups;

// Problem constants: B=4, K=8, H=W=64 -> N=4096, D=64, codes are 8-bit.
#define BATCH  4
#define KBITS  8
#define NPOS   4096
#define DDIM   64
#define NCODES 256
#define NBLK   1024   // 256 CUs * 4 blocks/CU -> exactly co-resident

// ---------------------------------------------------------------------------
// Fused cooperative kernel: 3 phases separated by grid.sync().
//   A (blocks 0..63): codes from z>0.5, per-256-pos LDS histogram of evidence
//      codes -> non-atomic partial hist store (no pre-zero memset needed).
//   B (all 1024 blocks = (b,cq)): sum 16 partials, per-code weight
//      wrow[c] = cnt*exp((mn-pop(cq^c))/t), branchless 64-codes-per-wave FMA
//      over value_table, cross-wave LDS reduce -> rowg[b][cq][d].
//   C (all blocks): gather out[(b*D+d)*N+n] = rowg[b][codes[b][n]][d],
//      uchar4 code load + float4 store.
// All-masked batch (mn stays 99) -> weights 0 -> output 0 (matches ref).
// ---------------------------------------------------------------------------
__global__ __launch_bounds__(256, 4)
void k_fused(const float* __restrict__ z,
             const int* __restrict__ evidence_mask,
             const float* __restrict__ temperature,
             const float* __restrict__ value_table,
             unsigned char* __restrict__ codes,
             int* __restrict__ hist_part,   // [B*16][256]
             float* __restrict__ rowg,      // [B][256][64]
             float* __restrict__ out) {
    const int bi  = blockIdx.x;
    const int tid = threadIdx.x;

    __shared__ int   h[NCODES];
    __shared__ float wrow[NCODES];
    __shared__ float accs[4][DDIM];
    __shared__ float dens[4];
    __shared__ int   mns[4];

    cg::grid_group grid = cg::this_grid();

    // ---- phase A: codes + partial histograms (first 64 blocks) ----------
    if (bi < BATCH * 16) {                    // block-uniform branch
        const int b = bi >> 4;
        const int n = (bi & 15) * 256 + tid;
        h[tid] = 0;
        __syncthreads();
        const float* zb = z + (size_t)b * KBITS * NPOS;
        int code = 0;
#pragma unroll
        for (int k = 0; k < KBITS; ++k)
            code |= (int)(zb[k * NPOS + n] > 0.5f) << k;
        codes[b * NPOS + n] = (unsigned char)code;
        if (evidence_mask[b * NPOS + n] != 0) atomicAdd(&h[code], 1);
        __syncthreads();
        hist_part[bi * NCODES + tid] = h[tid];   // coalesced, non-atomic
    }

    grid.sync();

    // ---- phase B: per-(b,cq) table row -----------------------------------
    {
        const int b  = bi >> 8;
        const int cq = bi & 255;
        const int wv = tid >> 6;          // wave 0..3
        const int d  = tid & 63;          // lane / output dim

        int cnt = 0;
#pragma unroll
        for (int j = 0; j < 16; ++j)
            cnt += hist_part[(b * 16 + j) * NCODES + tid];

        const int pop = __popc(cq ^ tid);
        int myMn = (cnt > 0) ? pop : 99;
#pragma unroll
        for (int off = 32; off > 0; off >>= 1)
            myMn = min(myMn, __shfl_down(myMn, off));
        if (d == 0) mns[wv] = myMn;
        __syncthreads();
        const int mn = min(min(mns[0], mns[1]), min(mns[2], mns[3]));

        const float inv_t = 1.0f / fmaxf(temperature[0], 0.1f);
        wrow[tid] = (mn > KBITS) ? 0.0f
                                 : (float)cnt * __expf((float)(mn - pop) * inv_t);
        __syncthreads();

        float acc = 0.0f, den = 0.0f;
#pragma unroll
        for (int i = 0; i < 64; ++i) {
            const int cc = wv * 64 + i;
            const float w = wrow[cc];                 // uniform addr: broadcast
            den += w;
            acc = fmaf(w, value_table[cc * DDIM + d], acc);
        }
        accs[wv][d] = acc;
        if (d == 0) dens[wv] = den;
        __syncthreads();
        if (wv == 0) {
            float a  = accs[0][d] + accs[1][d] + accs[2][d] + accs[3][d];
            float dn = dens[0] + dens[1] + dens[2] + dens[3];
            rowg[(((b << 8) + cq) << 6) + d] = a / fmaxf(dn, 1e-20f);
        }
    }

    grid.sync();

    // ---- phase C: gather --------------------------------------------------
    {
        const int gid  = bi * 256 + tid;
        const int base = gid * 4;                 // element index
        const int n4   = base & (NPOS - 1);       // multiple of 4
        const int bd   = base >> 12;              // NPOS = 2^12
        const int d    = bd & (DDIM - 1);
        const int b    = bd >> 6;

        const uchar4 c4 = *(const uchar4*)(codes + b * NPOS + n4);
        const float* rb = rowg + ((b << 8) << 6) + d;
        float4 o;
        o.x = rb[(int)c4.x << 6];
        o.y = rb[(int)c4.y << 6];
        o.z = rb[(int)c4.z << 6];
        o.w = rb[(int)c4.w << 6];
        *(float4*)(out + base) = o;
    }
}

// ---------------------------------------------------------------------------
// Fallback path (old 4-dispatch pipeline) in case cooperative launch is
// rejected (capture-unsupported / too-large). Identical math.
// ---------------------------------------------------------------------------
__global__ void k_codes_hist(const float* __restrict__ z,
                             const int* __restrict__ evidence_mask,
                             unsigned char* __restrict__ codes,
                             int* __restrict__ hist) {
    const int b  = blockIdx.x >> 4;
    const int n0 = (blockIdx.x & 15) * 256;
    const int tid = threadIdx.x;
    const int n = n0 + tid;

    __shared__ int h[NCODES];
    h[tid] = 0;
    __syncthreads();

    const float* zb = z + (size_t)b * KBITS * NPOS;
    int code = 0;
#pragma unroll
    for (int k = 0; k < KBITS; ++k)
        code |= (int)(zb[k * NPOS + n] > 0.5f) << k;
    codes[b * NPOS + n] = (unsigned char)code;
    if (evidence_mask[b * NPOS + n] != 0) atomicAdd(&h[code], 1);
    __syncthreads();
    if (h[tid] != 0) atomicAdd(&hist[b * NCODES + tid], h[tid]);
}

__global__ void k_table(const int* __restrict__ hist,
                        const float* __restrict__ value_table,
                        const float* __restrict__ temperature,
                        float* __restrict__ rowg) {
    const int b  = blockIdx.x >> 8;
    const int cq = blockIdx.x & 255;
    const int tid = threadIdx.x;
    const int wv  = tid >> 6;
    const int d   = tid & 63;

    __shared__ float wrow[NCODES];
    __shared__ float accs[4][DDIM];
    __shared__ float dens[4];
    __shared__ int   mns[4];

    const int cnt = hist[b * NCODES + tid];
    const int pop = __popc(cq ^ tid);
    int myMn = (cnt > 0) ? pop : 99;
#pragma unroll
    for (int off = 32; off > 0; off >>= 1) myMn = min(myMn, __shfl_down(myMn, off));
    if (d == 0) mns[wv] = myMn;
    __syncthreads();
    const int mn = min(min(mns[0], mns[1]), min(mns[2], mns[3]));

    const float inv_t = 1.0f / fmaxf(temperature[0], 0.1f);
    wrow[tid] = (mn > KBITS) ? 0.0f
                             : (float)cnt * __expf((float)(mn - pop) * inv_t);
    __syncthreads();

    float acc = 0.0f, den = 0.0f;
#pragma unroll
    for (int i = 0; i < 64; ++i) {
        const int cc = wv * 64 + i;
        const float w = wrow[cc];
        den += w;
        acc = fmaf(w, value_table[cc * DDIM + d], acc);
    }
    accs[wv][d] = acc;
    if (d == 0) dens[wv] = den;
    __syncthreads();
    if (wv == 0) {
        float a  = accs[0][d] + accs[1][d] + accs[2][d] + accs[3][d];
        float dn = dens[0] + dens[1] + dens[2] + dens[3];
        rowg[(((b << 8) + cq) << 6) + d] = a / fmaxf(dn, 1e-20f);
    }
}

__global__ void k_gather(const unsigned char* __restrict__ codes,
                         const float* __restrict__ rowg,
                         float* __restrict__ out) {
    const int gid  = blockIdx.x * 256 + threadIdx.x;
    const int base = gid * 4;
    const int n4   = base & (NPOS - 1);
    const int bd   = base >> 12;
    const int d    = bd & (DDIM - 1);
    const int b    = bd >> 6;

    const uchar4 c4 = *(const uchar4*)(codes + b * NPOS + n4);
    const float* rb = rowg + ((b << 8) << 6) + d;
    float4 o;
    o.x = rb[(int)c4.x << 6];
    o.y = rb[(int)c4.y << 6];
    o.z = rb[(int)c4.z << 6];
    o.w = rb[(int)c4.w << 6];
    *(float4*)(out + base) = o;
}

extern "C" void kernel_launch(void* const* d_in, const int* in_sizes, int n_in,
                              void* d_out, int out_size, void* d_ws, size_t ws_size,
                              hipStream_t stream) {
    const float* z           = (const float*)d_in[0];  // (B,K,H,W) fp32
    const int*   evidence    = (const int*)d_in[1];    // (B,N) bool->int32
    const float* temperature = (const float*)d_in[2];  // scalar
    const float* value_table = (const float*)d_in[3];  // (256,D) fp32
    // d_in[4] mask_value: never contributes (attn==0 off-evidence)
    // d_in[5] pop_lut: replaced by __popc

    float* out = (float*)d_out;  // (B,D,H,W) fp32

    unsigned char* codes     = (unsigned char*)d_ws;                     // 16384 B
    int*           hist_part = (int*)((char*)d_ws + 16384);              // 65536 B
    float*         rowg      = (float*)((char*)d_ws + 16384 + 65536);    // 262144 B

    void* args[] = {(void*)&z, (void*)&evidence, (void*)&temperature,
                    (void*)&value_table, (void*)&codes, (void*)&hist_part,
                    (void*)&rowg, (void*)&out};
    hipError_t err = hipLaunchCooperativeKernel((const void*)k_fused,
                                                dim3(NBLK), dim3(256),
                                                args, 0, stream);
    if (err != hipSuccess) {
        // Fallback: old 4-dispatch pipeline (hist reuses hist_part space).
        int* hist = (int*)((char*)d_ws + 16384);
        hipMemsetAsync(hist, 0, BATCH * NCODES * sizeof(int), stream);
        k_codes_hist<<<BATCH * 16, 256, 0, stream>>>(z, evidence, codes, hist);
        k_table<<<BATCH * NCODES, 256, 0, stream>>>(hist, value_table, temperature, rowg);
        k_gather<<<(BATCH * DDIM * NPOS) / (256 * 4), 256, 0, stream>>>(codes, rowg, out);
    }
}

// Round 2
// 83.516 us; speedup vs baseline: 3.6097x; 3.6097x over previous
//
#include <hip/hip_runtime.h>

// Problem constants: B=4, K=8, H=W=64 -> N=4096, D=64, codes are 8-bit.
#define BATCH  4
#define KBITS  8
#define NPOS   4096
#define DDIM   64
#define NCODES 256

// ---------------------------------------------------------------------------
// Single fused kernel, NO grid sync (round-1 showed grid.sync costs ~100us).
// Grid = B*256 blocks x 256 threads; block = (batch b, 16-position chunk).
// Cross-block dependency (per-batch histogram) is broken by redundant
// recompute: every block rebuilds the full batch histogram from z (z slice is
// 128 KB -> L2-resident; 1024 x 128 KB = 128 MB L2 traffic ~ 4 us).
//
// Math note: ref computes attn = exp((mn - pop)/t) stabilization; the e^{mn/t}
// factor is constant per query row and cancels in num/den, so we use
// w = cnt[c] * exp(-pop(cq^c)/t) directly. With temperature = 1.0 (bench
// input) the smallest weight is e^-8 ~ 3.4e-4: no underflow. All-masked
// batch -> all cnt = 0 -> den = 0 -> 1e-20 floor -> output 0 (matches ref).
// mask_value never contributes (attn == 0 off-evidence). pop_lut -> __popc.
// ---------------------------------------------------------------------------
__global__ __launch_bounds__(256, 4)
void k_all(const float* __restrict__ z,
           const int* __restrict__ evidence_mask,
           const float* __restrict__ temperature,
           const float* __restrict__ value_table,
           float* __restrict__ out) {
    const int bi    = blockIdx.x;
    const int b     = bi >> 8;        // batch
    const int chunk = bi & 255;       // 16-position chunk within batch
    const int tid   = threadIdx.x;

    __shared__ unsigned int codes_sh[NPOS / 4];   // 4 codes packed per word
    __shared__ int   h[NCODES];                   // evidence histogram
    __shared__ float w_sh[16][NCODES];            // per-chunk-position weights
    __shared__ float dens_sh[16];
    __shared__ float rows_sh[16][DDIM + 1];       // +1 pad: conflict-free transpose

    h[tid] = 0;
    __syncthreads();

    // ---- phase 1: codes + evidence histogram for the WHOLE batch ---------
    // thread handles 4 consecutive positions x 4 strided groups: float4/int4
    // coalesced; 4 codes pack into one u32 -> single conflict-free ds_write.
    const float* zb = z + (size_t)b * (KBITS * NPOS);
    const int*   eb = evidence_mask + b * NPOS;
#pragma unroll
    for (int i = 0; i < 4; ++i) {
        const int p = (i << 10) + (tid << 2);
        int c0 = 0, c1 = 0, c2 = 0, c3 = 0;
#pragma unroll
        for (int k = 0; k < KBITS; ++k) {
            const float4 v = *(const float4*)(zb + k * NPOS + p);
            c0 |= (int)(v.x > 0.5f) << k;
            c1 |= (int)(v.y > 0.5f) << k;
            c2 |= (int)(v.z > 0.5f) << k;
            c3 |= (int)(v.w > 0.5f) << k;
        }
        codes_sh[(i << 8) + tid] =
            (unsigned)c0 | ((unsigned)c1 << 8) | ((unsigned)c2 << 16) | ((unsigned)c3 << 24);
        const int4 e = *(const int4*)(eb + p);
        if (e.x) atomicAdd(&h[c0], 1);
        if (e.y) atomicAdd(&h[c1], 1);
        if (e.z) atomicAdd(&h[c2], 1);
        if (e.w) atomicAdd(&h[c3], 1);
    }
    __syncthreads();

    // ---- phase 2a: weight matrix w[16][256] for this chunk's codes --------
    const float inv_t = 1.0f / fmaxf(temperature[0], 0.1f);
    const float cntf  = (float)h[tid];
#pragma unroll
    for (int j = 0; j < 16; ++j) {
        const int cq = (codes_sh[(chunk << 2) + (j >> 2)] >> ((j & 3) << 3)) & 255;
        w_sh[j][tid] = cntf * __expf((float)__popc(cq ^ tid) * -inv_t);
    }
    __syncthreads();

    // ---- phase 2b: denominators (16 parallel 256-sums) --------------------
    {
        const int j  = tid >> 4;
        const int c0 = tid & 15;
        float s = 0.0f;
#pragma unroll
        for (int i = 0; i < 16; ++i) s += w_sh[j][c0 + (i << 4)];
#pragma unroll
        for (int m = 1; m < 16; m <<= 1) s += __shfl_xor(s, m, 16);
        if (c0 == 0) dens_sh[j] = fmaxf(s, 1e-20f);
    }
    __syncthreads();

    // ---- phase 2c: rows = W(16x256) * VT(256x64), wave wv owns 4 rows -----
    const int wv = tid >> 6;          // wave 0..3 -> rows {wv, wv+4, wv+8, wv+12}
    const int d  = tid & 63;          // lane = output dim (coalesced VT loads)
    float acc0 = 0.0f, acc1 = 0.0f, acc2 = 0.0f, acc3 = 0.0f;
    const float* vt = value_table + d;
    for (int c = 0; c < NCODES; c += 4) {
        const float v0 = vt[(c + 0) << 6];
        const float v1 = vt[(c + 1) << 6];
        const float v2 = vt[(c + 2) << 6];
        const float v3 = vt[(c + 3) << 6];
        const float4 wa = *(const float4*)&w_sh[wv     ][c];   // LDS broadcast
        const float4 wb = *(const float4*)&w_sh[wv + 4 ][c];
        const float4 wc = *(const float4*)&w_sh[wv + 8 ][c];
        const float4 wd = *(const float4*)&w_sh[wv + 12][c];
        acc0 = fmaf(wa.x, v0, fmaf(wa.y, v1, fmaf(wa.z, v2, fmaf(wa.w, v3, acc0))));
        acc1 = fmaf(wb.x, v0, fmaf(wb.y, v1, fmaf(wb.z, v2, fmaf(wb.w, v3, acc1))));
        acc2 = fmaf(wc.x, v0, fmaf(wc.y, v1, fmaf(wc.z, v2, fmaf(wc.w, v3, acc2))));
        acc3 = fmaf(wd.x, v0, fmaf(wd.y, v1, fmaf(wd.z, v2, fmaf(wd.w, v3, acc3))));
    }
    rows_sh[wv     ][d] = acc0 / dens_sh[wv     ];
    rows_sh[wv + 4 ][d] = acc1 / dens_sh[wv + 4 ];
    rows_sh[wv + 8 ][d] = acc2 / dens_sh[wv + 8 ];
    rows_sh[wv + 12][d] = acc3 / dens_sh[wv + 12];
    __syncthreads();

    // ---- phase 3: transposed coalesced store out[b, d, n0+j] --------------
    // 16-thread groups write 64 B contiguous runs; rows_sh pad -> 16 banks.
    float* ob = out + (size_t)b * DDIM * NPOS + (chunk << 4);
#pragma unroll
    for (int it = 0; it < 4; ++it) {
        const int idx = (it << 8) + tid;   // 0..1023
        const int j   = idx & 15;
        const int dd  = idx >> 4;
        ob[(size_t)dd * NPOS + j] = rows_sh[j][dd];
    }
}

extern "C" void kernel_launch(void* const* d_in, const int* in_sizes, int n_in,
                              void* d_out, int out_size, void* d_ws, size_t ws_size,
                              hipStream_t stream) {
    const float* z           = (const float*)d_in[0];  // (B,K,H,W) fp32
    const int*   evidence    = (const int*)d_in[1];    // (B,N) bool->int32
    const float* temperature = (const float*)d_in[2];  // scalar
    const float* value_table = (const float*)d_in[3];  // (256,D) fp32
    // d_in[4] mask_value: never contributes (attn==0 off-evidence)
    // d_in[5] pop_lut: replaced by __popc

    float* out = (float*)d_out;  // (B,D,H,W) fp32

    // Single plain dispatch: no workspace, no memset, no cooperative launch.
    k_all<<<BATCH * 256, 256, 0, stream>>>(z, evidence, temperature,
                                           value_table, out);
}